// Round 20
// baseline (43.182 us; speedup 1.0000x reference)
//
#include <hip/hip_runtime.h>
#include <hip/hip_bf16.h>
#include <math.h>

using bf16x8 = __attribute__((ext_vector_type(8))) __bf16;
using bf16x4 = __attribute__((ext_vector_type(4))) __bf16;
using f32x4  = __attribute__((ext_vector_type(4))) float;
using f32x16 = __attribute__((ext_vector_type(16))) float;

static constexpr int SEQ = 4096;
static constexpr int DIM = 64;
static constexpr int NB  = 4;
// 0.125 (1/sqrt(64)) * log2(e): scores in log2 domain -> exp2 everywhere
static constexpr float QSCALE = 0.18033688011112042f;

__device__ __forceinline__ float fast_exp2(float x) {
#if __has_builtin(__builtin_amdgcn_exp2f)
    return __builtin_amdgcn_exp2f(x);
#else
    return exp2f(x);
#endif
}

// ---------------------------------------------------------------------------
// Kernel 0: W cast+transpose -> WT[slot][out][d] bf16 (24 KB).
// ---------------------------------------------------------------------------
__global__ __launch_bounds__(256)
void wprep_kernel(const float* __restrict__ w, __bf16* __restrict__ WT)
{
    const int idx = (int)blockIdx.x * 256 + (int)threadIdx.x;  // < 3*64*64
    const int s = idx >> 12;
    const int o = (idx >> 6) & 63;
    const int d = idx & 63;
    WT[idx] = (__bf16)w[(s * DIM + d) * DIM + o];
}

// ---------------------------------------------------------------------------
// Kernel 1: fused pos-embed + QKV projection, SLOT-SPLIT grid (256, 3):
// blockIdx.y picks the slot -> 768 blocks = 3072 waves = 3 waves/SIMD
// (was 256 blocks = 1 wave/SIMD — the prep-side occupancy hole). Trig is
// recomputed per slot (3x, ~100 VALU cyc/thread) — cheap vs 3x latency
// hiding. Per-slot math and store layouts byte-identical to R17/R18.
// Q/K: swapped mfma(wf, xa); frag region (c32, d4): lane l elem e =
//   OUT[c32*32+(l&31)][d4*16 + 8*(l>>5) + e]; bf16x4 coalesced stores.
// V: normal mfma; frag (kc, ks, dt) lane l elem e =
//   V[kc*32 + ks*16 + (e&3)+8*(e>>2)+4*(l>>5)][dt*32 + (l&31)].
// Q pre-scaled by QSCALE (log2 domain).
// ---------------------------------------------------------------------------
__global__ __launch_bounds__(256)
void qkv_prep_kernel(const float* __restrict__ x, const __bf16* __restrict__ WT,
                     __bf16* __restrict__ Qf, __bf16* __restrict__ Kf,
                     __bf16* __restrict__ Vf)
{
    const int tid  = (int)threadIdx.x;
    const int lane = tid & 63;
    const int g  = lane >> 4;
    const int cl = lane & 15;
    const int rowbase = (int)blockIdx.x * 64 + (tid >> 6) * 16;  // in [0, B*S)
    const int slot    = (int)blockIdx.y;                          // 0=Q 1=K 2=V

    const int row  = rowbase + cl;
    const int spos = row & (SEQ - 1);
    const float fpos = (float)spos;
    bf16x8 xa[2];
#pragma unroll
    for (int h = 0; h < 2; ++h) {
        const float* xp = x + (long)row * DIM + 32*h + 8*g;
        f32x4 x0 = *reinterpret_cast<const f32x4*>(xp);
        f32x4 x1 = *reinterpret_cast<const f32x4*>(xp + 4);
        bf16x8 v;
#pragma unroll
        for (int e = 0; e < 8; ++e) {
            const int c = 32*h + 8*g + e;
            const float invf = exp2f(-13.287712379549449f * ((float)c * 0.03125f));
            const float pe   = __sinf(fpos * invf);
            const float xv   = (e < 4) ? x0[e] : x1[e - 4];
            v[e] = (__bf16)(xv + pe);
        }
        xa[h] = v;
    }

    const int bi  = rowbase >> 12;
    const int sp  = rowbase & (SEQ - 1);
    const int c32 = sp >> 5;
    const int rb16 = sp & 16;

    const __bf16* wt = WT + slot * DIM * DIM;
    f32x4 acc[4];
#pragma unroll
    for (int nt = 0; nt < 4; ++nt) acc[nt] = (f32x4){0.f, 0.f, 0.f, 0.f};
#pragma unroll
    for (int nt = 0; nt < 4; ++nt) {
        bf16x8 w0 = *reinterpret_cast<const bf16x8*>(wt + (nt*16 + cl) * DIM + 8*g);
        bf16x8 w1 = *reinterpret_cast<const bf16x8*>(wt + (nt*16 + cl) * DIM + 32 + 8*g);
        if (slot < 2) {   // swapped: lane -> seq, regs -> feature
            acc[nt] = __builtin_amdgcn_mfma_f32_16x16x32_bf16(w0, xa[0], acc[nt], 0, 0, 0);
            acc[nt] = __builtin_amdgcn_mfma_f32_16x16x32_bf16(w1, xa[1], acc[nt], 0, 0, 0);
        } else {          // normal: lane -> feature, regs -> seq
            acc[nt] = __builtin_amdgcn_mfma_f32_16x16x32_bf16(xa[0], w0, acc[nt], 0, 0, 0);
            acc[nt] = __builtin_amdgcn_mfma_f32_16x16x32_bf16(xa[1], w1, acc[nt], 0, 0, 0);
        }
    }

    if (slot < 2) {
        __bf16* dst = (slot == 0) ? Qf : Kf;
        const float scale = (slot == 0) ? QSCALE : 1.0f;
        __bf16* base = dst + ((long)(bi*128 + c32) * 4) * 512
                     + (rb16 + cl + 32*(g >> 1)) * 8 + 4*(g & 1);
#pragma unroll
        for (int nt = 0; nt < 4; ++nt) {
            bf16x4 pk;
#pragma unroll
            for (int r = 0; r < 4; ++r) pk[r] = (__bf16)(acc[nt][r] * scale);
            *reinterpret_cast<bf16x4*>(base + nt*512) = pk;
        }
    } else {
        const int ks  = (sp >> 4) & 1;
        const int lde = (32*(g&1) + cl)*8 + (g>>1)*4;   // + 128 for nt&1
        __bf16* vb = Vf + (((long)bi*128 + c32)*4 + ks*2)*512;
#pragma unroll
        for (int nt = 0; nt < 4; ++nt) {
            bf16x4 pk;
#pragma unroll
            for (int r = 0; r < 4; ++r) pk[r] = (__bf16)acc[nt][r];
            *reinterpret_cast<bf16x4*>(vb + (nt>>1)*512 + (nt&1)*128 + lde) = pk;
        }
    }
}

// ---------------------------------------------------------------------------
// Kernel 2: flash attention — EXACT R19 (best validated, 42.3 µs total).
// ZERO-LDS loop, NO-MAX softmax, 512-thr blocks, 8 waves share one 32-q
// tile, wave w owns k-range [w*512,+512) (16 tiles of 32 k), grid 512,
// XCD swizzle b=f(bid&7), race-free cascade epilogue (pure adds).
// ---------------------------------------------------------------------------
__global__ __launch_bounds__(512, 2)
void attn_kernel(const __bf16* __restrict__ Qf, const __bf16* __restrict__ Kf,
                 const __bf16* __restrict__ Vf, float* __restrict__ out)
{
    __shared__ char smem[35840];   // lpart[4][32][68] f32 (34816) + lls[8][32]
    float* lpart = (float*)smem;
    float* lls   = (float*)(smem + 34816);

    const int tid  = (int)threadIdx.x;
    const int w    = tid >> 6;     // k-range 0..7
    const int lane = tid & 63;
    const int hi   = lane >> 5;
    const int l31  = lane & 31;

    const int bid = (int)blockIdx.x;
    const int x8  = bid & 7;
    const int b   = x8 & 3;
    const int qt32 = ((x8 >> 2) << 6) | (bid >> 3);   // [0,128), bijective
    const int qbase = qt32 * 32;

    const __bf16* Qfp = Qf + ((long)(b*128 + qt32) * 4) * 512 + lane*8;
    const __bf16* Kfp = Kf + ((long)(b*128 + w*16) * 4) * 512 + lane*8;
    const __bf16* Vfp = Vf + ((long)(b*128 + w*16) * 4) * 512 + lane*8;

    // Q fragments (once, coalesced)
    bf16x8 qf[4];
#pragma unroll
    for (int d4 = 0; d4 < 4; ++d4)
        qf[d4] = *reinterpret_cast<const bf16x8*>(Qfp + d4*512);

    f32x16 acc[2];
#pragma unroll
    for (int dt = 0; dt < 2; ++dt)
#pragma unroll
        for (int r = 0; r < 16; ++r) acc[dt][r] = 0.f;
    float lsum = 0.f;

    // prologue: load K(0) fully
    bf16x8 kc0 = *reinterpret_cast<const bf16x8*>(Kfp);
    bf16x8 kc1 = *reinterpret_cast<const bf16x8*>(Kfp + 512);
    bf16x8 kc2 = *reinterpret_cast<const bf16x8*>(Kfp + 1024);
    bf16x8 kc3 = *reinterpret_cast<const bf16x8*>(Kfp + 1536);

#pragma unroll 2
    for (int n = 0; n < 16; ++n) {
        // ---- iter-start loads: V(n) x4 and K(n+1) frags 0,1 ----
        bf16x8 vc0 = *reinterpret_cast<const bf16x8*>(Vfp + n*2048);
        bf16x8 vc1 = *reinterpret_cast<const bf16x8*>(Vfp + n*2048 + 512);
        bf16x8 vc2 = *reinterpret_cast<const bf16x8*>(Vfp + n*2048 + 1024);
        bf16x8 vc3 = *reinterpret_cast<const bf16x8*>(Vfp + n*2048 + 1536);
        bf16x8 kn0, kn1, kn2, kn3;
        if (n < 15) {
            kn0 = *reinterpret_cast<const bf16x8*>(Kfp + (n+1)*2048);
            kn1 = *reinterpret_cast<const bf16x8*>(Kfp + (n+1)*2048 + 512);
        }

        // ---- QK^T: one 32x32 tile, d=64 -> 4 MFMA ----
        f32x16 s;
#pragma unroll
        for (int r = 0; r < 16; ++r) s[r] = 0.f;
        __builtin_amdgcn_s_setprio(1);
        s = __builtin_amdgcn_mfma_f32_32x32x16_bf16(kc0, qf[0], s, 0, 0, 0);
        s = __builtin_amdgcn_mfma_f32_32x32x16_bf16(kc1, qf[1], s, 0, 0, 0);
        s = __builtin_amdgcn_mfma_f32_32x32x16_bf16(kc2, qf[2], s, 0, 0, 0);
        s = __builtin_amdgcn_mfma_f32_32x32x16_bf16(kc3, qf[3], s, 0, 0, 0);
        __builtin_amdgcn_s_setprio(0);
        // s[r] = score_log2(q=l31, k = n*32 + (r&3)+8*(r>>2)+4*hi)

        // ---- late K(n+1) frags 2,3 (kc regs dead; cover = sm+PV) ----
        if (n < 15) {
            kn2 = *reinterpret_cast<const bf16x8*>(Kfp + (n+1)*2048 + 1024);
            kn3 = *reinterpret_cast<const bf16x8*>(Kfp + (n+1)*2048 + 1536);
        }

        // ---- NO-MAX softmax: P = exp2(s) directly (16 independent exp2) ----
        float ps0 = 0.f, ps1 = 0.f, ps2 = 0.f, ps3 = 0.f;
#pragma unroll
        for (int r = 0; r < 4; ++r) {
            const float p0 = fast_exp2(s[r]);
            const float p1 = fast_exp2(s[4 + r]);
            const float p2 = fast_exp2(s[8 + r]);
            const float p3 = fast_exp2(s[12 + r]);
            s[r] = p0; s[4 + r] = p1; s[8 + r] = p2; s[12 + r] = p3;
            ps0 += p0; ps1 += p1; ps2 += p2; ps3 += p3;
        }
        lsum += (ps0 + ps1) + (ps2 + ps3);

        // ---- P pack (B-operand), slot e -> k-pattern (e&3)+8(e>>2)+4hi ----
        bf16x8 pb0, pb1;
#pragma unroll
        for (int e = 0; e < 8; ++e) { pb0[e] = (__bf16)s[e]; pb1[e] = (__bf16)s[8 + e]; }

        // ---- PV transposed: acc[dt] = mfma(V^T frag, P frag) ----
        __builtin_amdgcn_s_setprio(1);
        acc[0] = __builtin_amdgcn_mfma_f32_32x32x16_bf16(vc0, pb0, acc[0], 0, 0, 0);
        acc[1] = __builtin_amdgcn_mfma_f32_32x32x16_bf16(vc1, pb0, acc[1], 0, 0, 0);
        acc[0] = __builtin_amdgcn_mfma_f32_32x32x16_bf16(vc2, pb1, acc[0], 0, 0, 0);
        acc[1] = __builtin_amdgcn_mfma_f32_32x32x16_bf16(vc3, pb1, acc[1], 0, 0, 0);
        __builtin_amdgcn_s_setprio(0);

        kc0 = kn0; kc1 = kn1; kc2 = kn2; kc3 = kn3;
    }

    // full row-sum across hi halves
    lsum += __shfl_xor(lsum, 32);

    // ---- race-free cascade 8->4->2->1 (pure ADDS, no m) ----
    auto write_slot = [&](int sl) {
        if (lane < 32) lls[sl*32 + l31] = lsum;
        float* pp = lpart + sl*2176 + l31*68;
#pragma unroll
        for (int dt = 0; dt < 2; ++dt)
#pragma unroll
            for (int j = 0; j < 4; ++j) {
                f32x4 v;
#pragma unroll
                for (int c = 0; c < 4; ++c) v[c] = acc[dt][4*j + c];
                *reinterpret_cast<f32x4*>(pp + dt*32 + 8*j + 4*hi) = v;
            }
    };
    auto merge_slot = [&](int sl) {
        lsum += lls[sl*32 + l31];
        const float* pp = lpart + sl*2176 + l31*68;
#pragma unroll
        for (int dt = 0; dt < 2; ++dt)
#pragma unroll
            for (int j = 0; j < 4; ++j) {
                f32x4 v = *reinterpret_cast<const f32x4*>(pp + dt*32 + 8*j + 4*hi);
#pragma unroll
                for (int c = 0; c < 4; ++c)
                    acc[dt][4*j + c] += v[c];
            }
    };

    if (w >= 4) write_slot(w - 4);
    __syncthreads();
    if (w < 4) merge_slot(w);
    if (w == 2 || w == 3) write_slot(w);      // own stage-1 slot: safe
    __syncthreads();
    if (w < 2) merge_slot(w + 2);
    if (w == 1) write_slot(1);                // own stage-1 slot: safe
    __syncthreads();
    if (w == 0) {
        merge_slot(1);
        const float inv = 1.f / lsum;
#pragma unroll
        for (int dt = 0; dt < 2; ++dt)
#pragma unroll
            for (int r = 0; r < 16; ++r) acc[dt][r] *= inv;
        write_slot(0);   // final normalized result -> slot 0
    }
    __syncthreads();

    // cooperative coalesced store: thread t -> q = t>>4 (0..31), dq = (t&15)*4
    {
        const int q  = tid >> 4;
        const int dq = (tid & 15) * 4;
        f32x4 o = *reinterpret_cast<const f32x4*>(lpart + q*68 + dq);
        *reinterpret_cast<f32x4*>(out + ((long)b * SEQ + qbase + q) * DIM + dq) = o;
    }
}

// ---------------------------------------------------------------------------
extern "C" void kernel_launch(void* const* d_in, const int* in_sizes, int n_in,
                              void* d_out, int out_size, void* d_ws, size_t ws_size,
                              hipStream_t stream)
{
    const float* x = (const float*)d_in[0];
    const float* w = (const float*)d_in[1];
    float* out = (float*)d_out;

    char* ws = (char*)d_ws;
    const size_t sz = (size_t)NB * SEQ * DIM * sizeof(__bf16);  // 2 MiB each
    __bf16* Qf  = (__bf16*)(ws);                        // frag-major Q
    __bf16* Kf  = (__bf16*)(ws + sz);                   // frag-major K
    __bf16* Vf  = (__bf16*)(ws + 2 * sz);               // frag-major V
    __bf16* WT  = (__bf16*)(ws + 3 * sz);               // 24 KiB

    wprep_kernel<<<3 * DIM * DIM / 256, 256, 0, stream>>>(w, WT);

    dim3 gp(NB * SEQ / 64, 3);   // slot-split: 768 blocks = 3 waves/SIMD
    qkv_prep_kernel<<<gp, 256, 0, stream>>>(x, WT, Qf, Kf, Vf);

    attn_kernel<<<NB * SEQ / 32, 512, 0, stream>>>(Qf, Kf, Vf, out);
}

// Round 21
// 42.739 us; speedup vs baseline: 1.0104x; 1.0104x over previous
//
#include <hip/hip_runtime.h>
#include <hip/hip_bf16.h>
#include <math.h>

using bf16x8 = __attribute__((ext_vector_type(8))) __bf16;
using bf16x4 = __attribute__((ext_vector_type(4))) __bf16;
using f32x4  = __attribute__((ext_vector_type(4))) float;
using f32x16 = __attribute__((ext_vector_type(16))) float;

static constexpr int SEQ = 4096;
static constexpr int DIM = 64;
static constexpr int NB  = 4;
// 0.125 (1/sqrt(64)) * log2(e): scores in log2 domain -> exp2 everywhere
static constexpr float QSCALE = 0.18033688011112042f;

__device__ __forceinline__ float fast_exp2(float x) {
#if __has_builtin(__builtin_amdgcn_exp2f)
    return __builtin_amdgcn_exp2f(x);
#else
    return exp2f(x);
#endif
}

// ---------------------------------------------------------------------------
// Kernel 0: W cast+transpose -> WT[slot][out][d] bf16 (24 KB).
// ---------------------------------------------------------------------------
__global__ __launch_bounds__(256)
void wprep_kernel(const float* __restrict__ w, __bf16* __restrict__ WT)
{
    const int idx = (int)blockIdx.x * 256 + (int)threadIdx.x;  // < 3*64*64
    const int s = idx >> 12;
    const int o = (idx >> 6) & 63;
    const int d = idx & 63;
    WT[idx] = (__bf16)w[(s * DIM + d) * DIM + o];
}

// ---------------------------------------------------------------------------
// Kernel 1: fused pos-embed + QKV projection, TWO-PHASE 768-thr block.
// Phase 1: threads 0..511 compute x' = x + pe for the block's 64 rows ONCE
//   (8 trig/thread) -> LDS [64][72] bf16 (+8 pad: ~2-way bank alias = free).
// Phase 2: 12 waves = 4 row-groups x 3 slots; each wave runs one slot's
//   MFMA + store for its 16 rows, xa frags ds_read from LDS (bit-identical
//   values to R19's register path). 256 blocks x 12 waves, 2 blocks/CU
//   -> 24 waves/CU (6/SIMD) with NO x-read or trig redundancy.
// Per-slot math/store layouts byte-identical to R19/R20 (verified):
// Q/K: swapped mfma(wf, xa); frag region (c32, d4): lane l elem e =
//   OUT[c32*32+(l&31)][d4*16 + 8*(l>>5) + e]; bf16x4 coalesced stores.
// V: normal mfma; frag (kc, ks, dt) lane l elem e =
//   V[kc*32 + ks*16 + (e&3)+8*(e>>2)+4*(l>>5)][dt*32 + (l&31)].
// Q pre-scaled by QSCALE (log2 domain).
// ---------------------------------------------------------------------------
__global__ __launch_bounds__(768)
void qkv_prep_kernel(const float* __restrict__ x, const __bf16* __restrict__ WT,
                     __bf16* __restrict__ Qf, __bf16* __restrict__ Kf,
                     __bf16* __restrict__ Vf)
{
    __shared__ __bf16 sxa[64][72];   // 9216 B

    const int tid = (int)threadIdx.x;
    const int blockrow = (int)blockIdx.x * 64;   // in [0, B*S)

    // ---- phase 1: x' = x + pos_embed for 64 rows, once per block ----
    if (tid < 512) {
        const int r  = tid >> 3;          // 0..63
        const int c0 = (tid & 7) * 8;     // 0,8,..,56
        const int row  = blockrow + r;
        const int spos = row & (SEQ - 1);
        const float fpos = (float)spos;
        const float* xp = x + (long)row * DIM + c0;
        f32x4 x0 = *reinterpret_cast<const f32x4*>(xp);
        f32x4 x1 = *reinterpret_cast<const f32x4*>(xp + 4);
        bf16x8 v;
#pragma unroll
        for (int e = 0; e < 8; ++e) {
            const int c = c0 + e;
            const float invf = exp2f(-13.287712379549449f * ((float)c * 0.03125f));
            const float pe   = __sinf(fpos * invf);
            const float xv   = (e < 4) ? x0[e] : x1[e - 4];
            v[e] = (__bf16)(xv + pe);
        }
        *reinterpret_cast<bf16x8*>(&sxa[r][c0]) = v;   // 16B aligned (144|16)
    }
    __syncthreads();

    // ---- phase 2: wave (rg, slot) does one slot x 16 rows ----
    const int w    = tid >> 6;
    const int lane = tid & 63;
    const int g  = lane >> 4;
    const int cl = lane & 15;
    const int rg   = w & 3;          // row-group 0..3
    const int slot = w >> 2;         // 0=Q 1=K 2=V
    const int rowbase = blockrow + rg * 16;

    bf16x8 xa[2];
#pragma unroll
    for (int h = 0; h < 2; ++h)
        xa[h] = *reinterpret_cast<const bf16x8*>(&sxa[rg*16 + cl][32*h + 8*g]);

    const int bi  = rowbase >> 12;
    const int sp  = rowbase & (SEQ - 1);
    const int c32 = sp >> 5;
    const int rb16 = sp & 16;

    const __bf16* wt = WT + slot * DIM * DIM;
    f32x4 acc[4];
#pragma unroll
    for (int nt = 0; nt < 4; ++nt) acc[nt] = (f32x4){0.f, 0.f, 0.f, 0.f};
#pragma unroll
    for (int nt = 0; nt < 4; ++nt) {
        bf16x8 w0 = *reinterpret_cast<const bf16x8*>(wt + (nt*16 + cl) * DIM + 8*g);
        bf16x8 w1 = *reinterpret_cast<const bf16x8*>(wt + (nt*16 + cl) * DIM + 32 + 8*g);
        if (slot < 2) {   // swapped: lane -> seq, regs -> feature
            acc[nt] = __builtin_amdgcn_mfma_f32_16x16x32_bf16(w0, xa[0], acc[nt], 0, 0, 0);
            acc[nt] = __builtin_amdgcn_mfma_f32_16x16x32_bf16(w1, xa[1], acc[nt], 0, 0, 0);
        } else {          // normal: lane -> feature, regs -> seq
            acc[nt] = __builtin_amdgcn_mfma_f32_16x16x32_bf16(xa[0], w0, acc[nt], 0, 0, 0);
            acc[nt] = __builtin_amdgcn_mfma_f32_16x16x32_bf16(xa[1], w1, acc[nt], 0, 0, 0);
        }
    }

    if (slot < 2) {
        __bf16* dst = (slot == 0) ? Qf : Kf;
        const float scale = (slot == 0) ? QSCALE : 1.0f;
        __bf16* base = dst + ((long)(bi*128 + c32) * 4) * 512
                     + (rb16 + cl + 32*(g >> 1)) * 8 + 4*(g & 1);
#pragma unroll
        for (int nt = 0; nt < 4; ++nt) {
            bf16x4 pk;
#pragma unroll
            for (int r = 0; r < 4; ++r) pk[r] = (__bf16)(acc[nt][r] * scale);
            *reinterpret_cast<bf16x4*>(base + nt*512) = pk;
        }
    } else {
        const int ks  = (sp >> 4) & 1;
        const int lde = (32*(g&1) + cl)*8 + (g>>1)*4;   // + 128 for nt&1
        __bf16* vb = Vf + (((long)bi*128 + c32)*4 + ks*2)*512;
#pragma unroll
        for (int nt = 0; nt < 4; ++nt) {
            bf16x4 pk;
#pragma unroll
            for (int r = 0; r < 4; ++r) pk[r] = (__bf16)acc[nt][r];
            *reinterpret_cast<bf16x4*>(vb + (nt>>1)*512 + (nt&1)*128 + lde) = pk;
        }
    }
}

// ---------------------------------------------------------------------------
// Kernel 2: flash attention — EXACT R19 (best validated, 42.3 µs total).
// ZERO-LDS loop, NO-MAX softmax, 512-thr blocks, 8 waves share one 32-q
// tile, wave w owns k-range [w*512,+512) (16 tiles of 32 k), grid 512,
// XCD swizzle b=f(bid&7), race-free cascade epilogue (pure adds).
// ---------------------------------------------------------------------------
__global__ __launch_bounds__(512, 2)
void attn_kernel(const __bf16* __restrict__ Qf, const __bf16* __restrict__ Kf,
                 const __bf16* __restrict__ Vf, float* __restrict__ out)
{
    __shared__ char smem[35840];   // lpart[4][32][68] f32 (34816) + lls[8][32]
    float* lpart = (float*)smem;
    float* lls   = (float*)(smem + 34816);

    const int tid  = (int)threadIdx.x;
    const int w    = tid >> 6;     // k-range 0..7
    const int lane = tid & 63;
    const int hi   = lane >> 5;
    const int l31  = lane & 31;

    const int bid = (int)blockIdx.x;
    const int x8  = bid & 7;
    const int b   = x8 & 3;
    const int qt32 = ((x8 >> 2) << 6) | (bid >> 3);   // [0,128), bijective
    const int qbase = qt32 * 32;

    const __bf16* Qfp = Qf + ((long)(b*128 + qt32) * 4) * 512 + lane*8;
    const __bf16* Kfp = Kf + ((long)(b*128 + w*16) * 4) * 512 + lane*8;
    const __bf16* Vfp = Vf + ((long)(b*128 + w*16) * 4) * 512 + lane*8;

    // Q fragments (once, coalesced)
    bf16x8 qf[4];
#pragma unroll
    for (int d4 = 0; d4 < 4; ++d4)
        qf[d4] = *reinterpret_cast<const bf16x8*>(Qfp + d4*512);

    f32x16 acc[2];
#pragma unroll
    for (int dt = 0; dt < 2; ++dt)
#pragma unroll
        for (int r = 0; r < 16; ++r) acc[dt][r] = 0.f;
    float lsum = 0.f;

    // prologue: load K(0) fully
    bf16x8 kc0 = *reinterpret_cast<const bf16x8*>(Kfp);
    bf16x8 kc1 = *reinterpret_cast<const bf16x8*>(Kfp + 512);
    bf16x8 kc2 = *reinterpret_cast<const bf16x8*>(Kfp + 1024);
    bf16x8 kc3 = *reinterpret_cast<const bf16x8*>(Kfp + 1536);

#pragma unroll 2
    for (int n = 0; n < 16; ++n) {
        // ---- iter-start loads: V(n) x4 and K(n+1) frags 0,1 ----
        bf16x8 vc0 = *reinterpret_cast<const bf16x8*>(Vfp + n*2048);
        bf16x8 vc1 = *reinterpret_cast<const bf16x8*>(Vfp + n*2048 + 512);
        bf16x8 vc2 = *reinterpret_cast<const bf16x8*>(Vfp + n*2048 + 1024);
        bf16x8 vc3 = *reinterpret_cast<const bf16x8*>(Vfp + n*2048 + 1536);
        bf16x8 kn0, kn1, kn2, kn3;
        if (n < 15) {
            kn0 = *reinterpret_cast<const bf16x8*>(Kfp + (n+1)*2048);
            kn1 = *reinterpret_cast<const bf16x8*>(Kfp + (n+1)*2048 + 512);
        }

        // ---- QK^T: one 32x32 tile, d=64 -> 4 MFMA ----
        f32x16 s;
#pragma unroll
        for (int r = 0; r < 16; ++r) s[r] = 0.f;
        __builtin_amdgcn_s_setprio(1);
        s = __builtin_amdgcn_mfma_f32_32x32x16_bf16(kc0, qf[0], s, 0, 0, 0);
        s = __builtin_amdgcn_mfma_f32_32x32x16_bf16(kc1, qf[1], s, 0, 0, 0);
        s = __builtin_amdgcn_mfma_f32_32x32x16_bf16(kc2, qf[2], s, 0, 0, 0);
        s = __builtin_amdgcn_mfma_f32_32x32x16_bf16(kc3, qf[3], s, 0, 0, 0);
        __builtin_amdgcn_s_setprio(0);
        // s[r] = score_log2(q=l31, k = n*32 + (r&3)+8*(r>>2)+4*hi)

        // ---- late K(n+1) frags 2,3 (kc regs dead; cover = sm+PV) ----
        if (n < 15) {
            kn2 = *reinterpret_cast<const bf16x8*>(Kfp + (n+1)*2048 + 1024);
            kn3 = *reinterpret_cast<const bf16x8*>(Kfp + (n+1)*2048 + 1536);
        }

        // ---- NO-MAX softmax: P = exp2(s) directly (16 independent exp2) ----
        float ps0 = 0.f, ps1 = 0.f, ps2 = 0.f, ps3 = 0.f;
#pragma unroll
        for (int r = 0; r < 4; ++r) {
            const float p0 = fast_exp2(s[r]);
            const float p1 = fast_exp2(s[4 + r]);
            const float p2 = fast_exp2(s[8 + r]);
            const float p3 = fast_exp2(s[12 + r]);
            s[r] = p0; s[4 + r] = p1; s[8 + r] = p2; s[12 + r] = p3;
            ps0 += p0; ps1 += p1; ps2 += p2; ps3 += p3;
        }
        lsum += (ps0 + ps1) + (ps2 + ps3);

        // ---- P pack (B-operand), slot e -> k-pattern (e&3)+8(e>>2)+4hi ----
        bf16x8 pb0, pb1;
#pragma unroll
        for (int e = 0; e < 8; ++e) { pb0[e] = (__bf16)s[e]; pb1[e] = (__bf16)s[8 + e]; }

        // ---- PV transposed: acc[dt] = mfma(V^T frag, P frag) ----
        __builtin_amdgcn_s_setprio(1);
        acc[0] = __builtin_amdgcn_mfma_f32_32x32x16_bf16(vc0, pb0, acc[0], 0, 0, 0);
        acc[1] = __builtin_amdgcn_mfma_f32_32x32x16_bf16(vc1, pb0, acc[1], 0, 0, 0);
        acc[0] = __builtin_amdgcn_mfma_f32_32x32x16_bf16(vc2, pb1, acc[0], 0, 0, 0);
        acc[1] = __builtin_amdgcn_mfma_f32_32x32x16_bf16(vc3, pb1, acc[1], 0, 0, 0);
        __builtin_amdgcn_s_setprio(0);

        kc0 = kn0; kc1 = kn1; kc2 = kn2; kc3 = kn3;
    }

    // full row-sum across hi halves
    lsum += __shfl_xor(lsum, 32);

    // ---- race-free cascade 8->4->2->1 (pure ADDS, no m) ----
    auto write_slot = [&](int sl) {
        if (lane < 32) lls[sl*32 + l31] = lsum;
        float* pp = lpart + sl*2176 + l31*68;
#pragma unroll
        for (int dt = 0; dt < 2; ++dt)
#pragma unroll
            for (int j = 0; j < 4; ++j) {
                f32x4 v;
#pragma unroll
                for (int c = 0; c < 4; ++c) v[c] = acc[dt][4*j + c];
                *reinterpret_cast<f32x4*>(pp + dt*32 + 8*j + 4*hi) = v;
            }
    };
    auto merge_slot = [&](int sl) {
        lsum += lls[sl*32 + l31];
        const float* pp = lpart + sl*2176 + l31*68;
#pragma unroll
        for (int dt = 0; dt < 2; ++dt)
#pragma unroll
            for (int j = 0; j < 4; ++j) {
                f32x4 v = *reinterpret_cast<const f32x4*>(pp + dt*32 + 8*j + 4*hi);
#pragma unroll
                for (int c = 0; c < 4; ++c)
                    acc[dt][4*j + c] += v[c];
            }
    };

    if (w >= 4) write_slot(w - 4);
    __syncthreads();
    if (w < 4) merge_slot(w);
    if (w == 2 || w == 3) write_slot(w);      // own stage-1 slot: safe
    __syncthreads();
    if (w < 2) merge_slot(w + 2);
    if (w == 1) write_slot(1);                // own stage-1 slot: safe
    __syncthreads();
    if (w == 0) {
        merge_slot(1);
        const float inv = 1.f / lsum;
#pragma unroll
        for (int dt = 0; dt < 2; ++dt)
#pragma unroll
            for (int r = 0; r < 16; ++r) acc[dt][r] *= inv;
        write_slot(0);   // final normalized result -> slot 0
    }
    __syncthreads();

    // cooperative coalesced store: thread t -> q = t>>4 (0..31), dq = (t&15)*4
    {
        const int q  = tid >> 4;
        const int dq = (tid & 15) * 4;
        f32x4 o = *reinterpret_cast<const f32x4*>(lpart + q*68 + dq);
        *reinterpret_cast<f32x4*>(out + ((long)b * SEQ + qbase + q) * DIM + dq) = o;
    }
}

// ---------------------------------------------------------------------------
extern "C" void kernel_launch(void* const* d_in, const int* in_sizes, int n_in,
                              void* d_out, int out_size, void* d_ws, size_t ws_size,
                              hipStream_t stream)
{
    const float* x = (const float*)d_in[0];
    const float* w = (const float*)d_in[1];
    float* out = (float*)d_out;

    char* ws = (char*)d_ws;
    const size_t sz = (size_t)NB * SEQ * DIM * sizeof(__bf16);  // 2 MiB each
    __bf16* Qf  = (__bf16*)(ws);                        // frag-major Q
    __bf16* Kf  = (__bf16*)(ws + sz);                   // frag-major K
    __bf16* Vf  = (__bf16*)(ws + 2 * sz);               // frag-major V
    __bf16* WT  = (__bf16*)(ws + 3 * sz);               // 24 KiB

    wprep_kernel<<<3 * DIM * DIM / 256, 256, 0, stream>>>(w, WT);

    qkv_prep_kernel<<<NB * SEQ / 64, 768, 0, stream>>>(x, WT, Qf, Kf, Vf);

    attn_kernel<<<NB * SEQ / 32, 512, 0, stream>>>(Qf, Kf, Vf, out);
}

// Round 22
// 42.127 us; speedup vs baseline: 1.0250x; 1.0145x over previous
//
#include <hip/hip_runtime.h>
#include <hip/hip_bf16.h>
#include <math.h>

using bf16x8 = __attribute__((ext_vector_type(8))) __bf16;
using bf16x4 = __attribute__((ext_vector_type(4))) __bf16;
using f32x4  = __attribute__((ext_vector_type(4))) float;
using f32x16 = __attribute__((ext_vector_type(16))) float;

static constexpr int SEQ = 4096;
static constexpr int DIM = 64;
static constexpr int NB  = 4;
// 0.125 (1/sqrt(64)) * log2(e): scores in log2 domain -> exp2 everywhere
static constexpr float QSCALE = 0.18033688011112042f;

__device__ __forceinline__ float fast_exp2(float x) {
#if __has_builtin(__builtin_amdgcn_exp2f)
    return __builtin_amdgcn_exp2f(x);
#else
    return exp2f(x);
#endif
}

// ---------------------------------------------------------------------------
// Kernel 0: W cast+transpose -> WT[slot][out][d] bf16 (24 KB).
// ---------------------------------------------------------------------------
__global__ __launch_bounds__(256)
void wprep_kernel(const float* __restrict__ w, __bf16* __restrict__ WT)
{
    const int idx = (int)blockIdx.x * 256 + (int)threadIdx.x;  // < 3*64*64
    const int s = idx >> 12;
    const int o = (idx >> 6) & 63;
    const int d = idx & 63;
    WT[idx] = (__bf16)w[(s * DIM + d) * DIM + o];
}

// ---------------------------------------------------------------------------
// Kernel 1: fused pos-embed + QKV projection (EXACT R19 — best validated).
// Single-pass: 256 thr (4 waves, 16 rows each), all 3 slots per block.
// R20 (slot-split, 3x occupancy) and R21 (two-phase LDS, 6x occupancy) were
// both WORSE — prep is launch/bandwidth-bound, not occupancy-bound.
// Q/K: swapped mfma(wf, xa); frag region (c32, d4): lane l elem e =
//   OUT[c32*32+(l&31)][d4*16 + 8*(l>>5) + e]; bf16x4 coalesced stores.
// V: normal mfma; frag (kc, ks, dt) lane l elem e =
//   V[kc*32 + ks*16 + (e&3)+8*(e>>2)+4*(l>>5)][dt*32 + (l&31)].
// Q pre-scaled by QSCALE (log2 domain). Inline trig (bit-identical).
// ---------------------------------------------------------------------------
__global__ __launch_bounds__(256)
void qkv_prep_kernel(const float* __restrict__ x, const __bf16* __restrict__ WT,
                     __bf16* __restrict__ Qf, __bf16* __restrict__ Kf,
                     __bf16* __restrict__ Vf)
{
    const int tid  = (int)threadIdx.x;
    const int lane = tid & 63;
    const int g  = lane >> 4;
    const int cl = lane & 15;
    const int rowbase = (int)blockIdx.x * 64 + (tid >> 6) * 16;  // in [0, B*S)

    const int row  = rowbase + cl;
    const int spos = row & (SEQ - 1);
    const float fpos = (float)spos;
    bf16x8 xa[2];
#pragma unroll
    for (int h = 0; h < 2; ++h) {
        const float* xp = x + (long)row * DIM + 32*h + 8*g;
        f32x4 x0 = *reinterpret_cast<const f32x4*>(xp);
        f32x4 x1 = *reinterpret_cast<const f32x4*>(xp + 4);
        bf16x8 v;
#pragma unroll
        for (int e = 0; e < 8; ++e) {
            const int c = 32*h + 8*g + e;
            const float invf = exp2f(-13.287712379549449f * ((float)c * 0.03125f));
            const float pe   = __sinf(fpos * invf);
            const float xv   = (e < 4) ? x0[e] : x1[e - 4];
            v[e] = (__bf16)(xv + pe);
        }
        xa[h] = v;
    }

    const int bi  = rowbase >> 12;
    const int sp  = rowbase & (SEQ - 1);
    const int c32 = sp >> 5;
    const int rb16 = sp & 16;

#pragma unroll
    for (int slot = 0; slot < 3; ++slot) {
        const __bf16* wt = WT + slot * DIM * DIM;
        f32x4 acc[4];
#pragma unroll
        for (int nt = 0; nt < 4; ++nt) acc[nt] = (f32x4){0.f, 0.f, 0.f, 0.f};
#pragma unroll
        for (int nt = 0; nt < 4; ++nt) {
            bf16x8 w0 = *reinterpret_cast<const bf16x8*>(wt + (nt*16 + cl) * DIM + 8*g);
            bf16x8 w1 = *reinterpret_cast<const bf16x8*>(wt + (nt*16 + cl) * DIM + 32 + 8*g);
            if (slot < 2) {   // swapped: lane -> seq, regs -> feature
                acc[nt] = __builtin_amdgcn_mfma_f32_16x16x32_bf16(w0, xa[0], acc[nt], 0, 0, 0);
                acc[nt] = __builtin_amdgcn_mfma_f32_16x16x32_bf16(w1, xa[1], acc[nt], 0, 0, 0);
            } else {          // normal: lane -> feature, regs -> seq
                acc[nt] = __builtin_amdgcn_mfma_f32_16x16x32_bf16(xa[0], w0, acc[nt], 0, 0, 0);
                acc[nt] = __builtin_amdgcn_mfma_f32_16x16x32_bf16(xa[1], w1, acc[nt], 0, 0, 0);
            }
        }

        if (slot < 2) {
            __bf16* dst = (slot == 0) ? Qf : Kf;
            const float scale = (slot == 0) ? QSCALE : 1.0f;
            __bf16* base = dst + ((long)(bi*128 + c32) * 4) * 512
                         + (rb16 + cl + 32*(g >> 1)) * 8 + 4*(g & 1);
#pragma unroll
            for (int nt = 0; nt < 4; ++nt) {
                bf16x4 pk;
#pragma unroll
                for (int r = 0; r < 4; ++r) pk[r] = (__bf16)(acc[nt][r] * scale);
                *reinterpret_cast<bf16x4*>(base + nt*512) = pk;
            }
        } else {
            const int ks  = (sp >> 4) & 1;
            const int lde = (32*(g&1) + cl)*8 + (g>>1)*4;   // + 128 for nt&1
            __bf16* vb = Vf + (((long)bi*128 + c32)*4 + ks*2)*512;
#pragma unroll
            for (int nt = 0; nt < 4; ++nt) {
                bf16x4 pk;
#pragma unroll
                for (int r = 0; r < 4; ++r) pk[r] = (__bf16)acc[nt][r];
                *reinterpret_cast<bf16x4*>(vb + (nt>>1)*512 + (nt&1)*128 + lde) = pk;
            }
        }
    }
}

// ---------------------------------------------------------------------------
// Kernel 2: flash attention — EXACT R19 (best validated, 42.3 µs total).
// ZERO-LDS loop, NO-MAX softmax, 512-thr blocks, 8 waves share one 32-q
// tile, wave w owns k-range [w*512,+512) (16 tiles of 32 k), grid 512,
// XCD swizzle b=f(bid&7), race-free cascade epilogue (pure adds).
// ---------------------------------------------------------------------------
__global__ __launch_bounds__(512, 2)
void attn_kernel(const __bf16* __restrict__ Qf, const __bf16* __restrict__ Kf,
                 const __bf16* __restrict__ Vf, float* __restrict__ out)
{
    __shared__ char smem[35840];   // lpart[4][32][68] f32 (34816) + lls[8][32]
    float* lpart = (float*)smem;
    float* lls   = (float*)(smem + 34816);

    const int tid  = (int)threadIdx.x;
    const int w    = tid >> 6;     // k-range 0..7
    const int lane = tid & 63;
    const int hi   = lane >> 5;
    const int l31  = lane & 31;

    const int bid = (int)blockIdx.x;
    const int x8  = bid & 7;
    const int b   = x8 & 3;
    const int qt32 = ((x8 >> 2) << 6) | (bid >> 3);   // [0,128), bijective
    const int qbase = qt32 * 32;

    const __bf16* Qfp = Qf + ((long)(b*128 + qt32) * 4) * 512 + lane*8;
    const __bf16* Kfp = Kf + ((long)(b*128 + w*16) * 4) * 512 + lane*8;
    const __bf16* Vfp = Vf + ((long)(b*128 + w*16) * 4) * 512 + lane*8;

    // Q fragments (once, coalesced)
    bf16x8 qf[4];
#pragma unroll
    for (int d4 = 0; d4 < 4; ++d4)
        qf[d4] = *reinterpret_cast<const bf16x8*>(Qfp + d4*512);

    f32x16 acc[2];
#pragma unroll
    for (int dt = 0; dt < 2; ++dt)
#pragma unroll
        for (int r = 0; r < 16; ++r) acc[dt][r] = 0.f;
    float lsum = 0.f;

    // prologue: load K(0) fully
    bf16x8 kc0 = *reinterpret_cast<const bf16x8*>(Kfp);
    bf16x8 kc1 = *reinterpret_cast<const bf16x8*>(Kfp + 512);
    bf16x8 kc2 = *reinterpret_cast<const bf16x8*>(Kfp + 1024);
    bf16x8 kc3 = *reinterpret_cast<const bf16x8*>(Kfp + 1536);

#pragma unroll 2
    for (int n = 0; n < 16; ++n) {
        // ---- iter-start loads: V(n) x4 and K(n+1) frags 0,1 ----
        bf16x8 vc0 = *reinterpret_cast<const bf16x8*>(Vfp + n*2048);
        bf16x8 vc1 = *reinterpret_cast<const bf16x8*>(Vfp + n*2048 + 512);
        bf16x8 vc2 = *reinterpret_cast<const bf16x8*>(Vfp + n*2048 + 1024);
        bf16x8 vc3 = *reinterpret_cast<const bf16x8*>(Vfp + n*2048 + 1536);
        bf16x8 kn0, kn1, kn2, kn3;
        if (n < 15) {
            kn0 = *reinterpret_cast<const bf16x8*>(Kfp + (n+1)*2048);
            kn1 = *reinterpret_cast<const bf16x8*>(Kfp + (n+1)*2048 + 512);
        }

        // ---- QK^T: one 32x32 tile, d=64 -> 4 MFMA ----
        f32x16 s;
#pragma unroll
        for (int r = 0; r < 16; ++r) s[r] = 0.f;
        __builtin_amdgcn_s_setprio(1);
        s = __builtin_amdgcn_mfma_f32_32x32x16_bf16(kc0, qf[0], s, 0, 0, 0);
        s = __builtin_amdgcn_mfma_f32_32x32x16_bf16(kc1, qf[1], s, 0, 0, 0);
        s = __builtin_amdgcn_mfma_f32_32x32x16_bf16(kc2, qf[2], s, 0, 0, 0);
        s = __builtin_amdgcn_mfma_f32_32x32x16_bf16(kc3, qf[3], s, 0, 0, 0);
        __builtin_amdgcn_s_setprio(0);
        // s[r] = score_log2(q=l31, k = n*32 + (r&3)+8*(r>>2)+4*hi)

        // ---- late K(n+1) frags 2,3 (kc regs dead; cover = sm+PV) ----
        if (n < 15) {
            kn2 = *reinterpret_cast<const bf16x8*>(Kfp + (n+1)*2048 + 1024);
            kn3 = *reinterpret_cast<const bf16x8*>(Kfp + (n+1)*2048 + 1536);
        }

        // ---- NO-MAX softmax: P = exp2(s) directly (16 independent exp2) ----
        float ps0 = 0.f, ps1 = 0.f, ps2 = 0.f, ps3 = 0.f;
#pragma unroll
        for (int r = 0; r < 4; ++r) {
            const float p0 = fast_exp2(s[r]);
            const float p1 = fast_exp2(s[4 + r]);
            const float p2 = fast_exp2(s[8 + r]);
            const float p3 = fast_exp2(s[12 + r]);
            s[r] = p0; s[4 + r] = p1; s[8 + r] = p2; s[12 + r] = p3;
            ps0 += p0; ps1 += p1; ps2 += p2; ps3 += p3;
        }
        lsum += (ps0 + ps1) + (ps2 + ps3);

        // ---- P pack (B-operand), slot e -> k-pattern (e&3)+8(e>>2)+4hi ----
        bf16x8 pb0, pb1;
#pragma unroll
        for (int e = 0; e < 8; ++e) { pb0[e] = (__bf16)s[e]; pb1[e] = (__bf16)s[8 + e]; }

        // ---- PV transposed: acc[dt] = mfma(V^T frag, P frag) ----
        __builtin_amdgcn_s_setprio(1);
        acc[0] = __builtin_amdgcn_mfma_f32_32x32x16_bf16(vc0, pb0, acc[0], 0, 0, 0);
        acc[1] = __builtin_amdgcn_mfma_f32_32x32x16_bf16(vc1, pb0, acc[1], 0, 0, 0);
        acc[0] = __builtin_amdgcn_mfma_f32_32x32x16_bf16(vc2, pb1, acc[0], 0, 0, 0);
        acc[1] = __builtin_amdgcn_mfma_f32_32x32x16_bf16(vc3, pb1, acc[1], 0, 0, 0);
        __builtin_amdgcn_s_setprio(0);

        kc0 = kn0; kc1 = kn1; kc2 = kn2; kc3 = kn3;
    }

    // full row-sum across hi halves
    lsum += __shfl_xor(lsum, 32);

    // ---- race-free cascade 8->4->2->1 (pure ADDS, no m) ----
    auto write_slot = [&](int sl) {
        if (lane < 32) lls[sl*32 + l31] = lsum;
        float* pp = lpart + sl*2176 + l31*68;
#pragma unroll
        for (int dt = 0; dt < 2; ++dt)
#pragma unroll
            for (int j = 0; j < 4; ++j) {
                f32x4 v;
#pragma unroll
                for (int c = 0; c < 4; ++c) v[c] = acc[dt][4*j + c];
                *reinterpret_cast<f32x4*>(pp + dt*32 + 8*j + 4*hi) = v;
            }
    };
    auto merge_slot = [&](int sl) {
        lsum += lls[sl*32 + l31];
        const float* pp = lpart + sl*2176 + l31*68;
#pragma unroll
        for (int dt = 0; dt < 2; ++dt)
#pragma unroll
            for (int j = 0; j < 4; ++j) {
                f32x4 v = *reinterpret_cast<const f32x4*>(pp + dt*32 + 8*j + 4*hi);
#pragma unroll
                for (int c = 0; c < 4; ++c)
                    acc[dt][4*j + c] += v[c];
            }
    };

    if (w >= 4) write_slot(w - 4);
    __syncthreads();
    if (w < 4) merge_slot(w);
    if (w == 2 || w == 3) write_slot(w);      // own stage-1 slot: safe
    __syncthreads();
    if (w < 2) merge_slot(w + 2);
    if (w == 1) write_slot(1);                // own stage-1 slot: safe
    __syncthreads();
    if (w == 0) {
        merge_slot(1);
        const float inv = 1.f / lsum;
#pragma unroll
        for (int dt = 0; dt < 2; ++dt)
#pragma unroll
            for (int r = 0; r < 16; ++r) acc[dt][r] *= inv;
        write_slot(0);   // final normalized result -> slot 0
    }
    __syncthreads();

    // cooperative coalesced store: thread t -> q = t>>4 (0..31), dq = (t&15)*4
    {
        const int q  = tid >> 4;
        const int dq = (tid & 15) * 4;
        f32x4 o = *reinterpret_cast<const f32x4*>(lpart + q*68 + dq);
        *reinterpret_cast<f32x4*>(out + ((long)b * SEQ + qbase + q) * DIM + dq) = o;
    }
}

// ---------------------------------------------------------------------------
extern "C" void kernel_launch(void* const* d_in, const int* in_sizes, int n_in,
                              void* d_out, int out_size, void* d_ws, size_t ws_size,
                              hipStream_t stream)
{
    const float* x = (const float*)d_in[0];
    const float* w = (const float*)d_in[1];
    float* out = (float*)d_out;

    char* ws = (char*)d_ws;
    const size_t sz = (size_t)NB * SEQ * DIM * sizeof(__bf16);  // 2 MiB each
    __bf16* Qf  = (__bf16*)(ws);                        // frag-major Q
    __bf16* Kf  = (__bf16*)(ws + sz);                   // frag-major K
    __bf16* Vf  = (__bf16*)(ws + 2 * sz);               // frag-major V
    __bf16* WT  = (__bf16*)(ws + 3 * sz);               // 24 KiB

    wprep_kernel<<<3 * DIM * DIM / 256, 256, 0, stream>>>(w, WT);

    qkv_prep_kernel<<<NB * SEQ / 64, 256, 0, stream>>>(x, WT, Qf, Kf, Vf);

    attn_kernel<<<NB * SEQ / 32, 512, 0, stream>>>(Qf, Kf, Vf, out);
}